// Round 4
// baseline (722.798 us; speedup 1.0000x reference)
//
#include <hip/hip_runtime.h>
#include <stdint.h>

#define TB_ 32
#define C_ 256
#define N_ 3136
#define TBC (C_ * N_)            // 802816 elems per (t,b) per 256-ch tensor
#define ACT_SZ (TB_ * TBC)       // 25690112
#define XSB_TB 819200            // u16 elems per tb in blocked xs (200 groups * 4096)
#define PARTS 4
#define CHUNK 784                // 3136/4, multiple of 4

typedef __attribute__((ext_vector_type(8))) short bf16x8;
typedef __attribute__((ext_vector_type(4))) float f32x4;

__device__ __forceinline__ void glds16(const void* gp, void* lp) {
  __builtin_amdgcn_global_load_lds(
      (const __attribute__((address_space(1))) unsigned int*)gp,
      (__attribute__((address_space(3))) unsigned int*)lp, 16, 0, 0);
}

__device__ __forceinline__ unsigned short bf16rn(float f, float* val) {
  unsigned b = __float_as_uint(f);
  unsigned r = (b + 0x7fffu + ((b >> 16) & 1u)) >> 16;
  *val = __uint_as_float(r << 16);
  return (unsigned short)r;
}

__device__ __forceinline__ int dot4u(unsigned a, unsigned b, int c) {
  c += (int)(a & 255u)         * (int)(b & 255u);
  c += (int)((a >> 8) & 255u)  * (int)((b >> 8) & 255u);
  c += (int)((a >> 16) & 255u) * (int)((b >> 16) & 255u);
  c += (int)(a >> 24)          * (int)(b >> 24);
  return c;
}

// bytes are 0..8 -> positive as signed i8, sdot4 is exact here
__device__ __forceinline__ int dot4(unsigned a, unsigned b, int c) {
#if defined(__has_builtin)
#if __has_builtin(__builtin_amdgcn_sdot4)
  return __builtin_amdgcn_sdot4((int)a, (int)b, c, false);
#else
  return dot4u(a, b, c);
#endif
#else
  return dot4u(a, b, c);
#endif
}

// ---------------------------------------------------------------------------
// K0: fold BN params
// ---------------------------------------------------------------------------
__global__ void bn_prep(const float* __restrict__ qbn, const float* __restrict__ kbn,
                        const float* __restrict__ vbn, const float* __restrict__ pbn,
                        float* __restrict__ bnw) {
  int c = threadIdx.x;
  const float* ps[4] = {qbn, kbn, vbn, pbn};
#pragma unroll
  for (int i = 0; i < 4; ++i) {
    const float* p = ps[i];
    float g = p[c], be = p[256 + c], mn = p[512 + c], vr = p[768 + c];
    float s = g / sqrtf(vr + 1e-5f);
    float b = __fsub_rn(be, __fmul_rn(mn, s));
    bnw[i * 512 + c] = s;
    bnw[i * 512 + 256 + c] = b;
  }
}

// ---------------------------------------------------------------------------
// K0b: exact 3-term bf16 split of fp32 weights into MFMA A-fragment images
// ---------------------------------------------------------------------------
__global__ void wprep(const float* __restrict__ qw, const float* __restrict__ kw,
                      const float* __restrict__ vw, const float* __restrict__ pw,
                      unsigned short* __restrict__ wsp) {
  const float* Ws[4] = {qw, kw, vw, pw};
  int m = blockIdx.y, co = blockIdx.x, k = threadIdx.x;
  float w = Ws[m][co * 256 + k];
  float h1, h2, h3r;
  unsigned short u1 = bf16rn(w, &h1);
  float r1 = __fsub_rn(w, h1);
  unsigned short u2 = bf16rn(r1, &h2);
  float r2 = __fsub_rn(r1, h2);
  unsigned short u3 = bf16rn(r2, &h3r);   // exact: r2 has <=8 significant bits
  int rt = co >> 7, ks = k >> 5;
  int lane = (co & 15) + 16 * ((k >> 3) & 3);
  unsigned short us[3] = {u1, u2, u3};
#pragma unroll
  for (int sp = 0; sp < 3; ++sp) {
    size_t off = (size_t)((((m * 3 + sp) * 2 + rt) * 8 + ks)) * 4096 + lane * 8 + (k & 7);
    wsp[off] = us[sp];
  }
}

// ---------------------------------------------------------------------------
// K1: x -> spikes (bf16, exact 0..8) in blocked B-fragment layout
// ---------------------------------------------------------------------------
__global__ __launch_bounds__(256) void quant_x_t(const float* __restrict__ x,
                                                 unsigned short* __restrict__ xsb) {
  __shared__ unsigned short s[64 * 65];
  const int t = threadIdx.x;
  const int n0 = blockIdx.x * 64;
  const int tb = blockIdx.y;
  const float* X = x + (size_t)tb * TBC;
  const int nl = t & 63, cq = t >> 6;

  unsigned short* dstb = xsb + (size_t)tb * XSB_TB;
  for (int cb = 0; cb < 4; ++cb) {
    int cbase = cb * 64;
#pragma unroll 4
    for (int i = 0; i < 16; ++i) {
      int c = i * 4 + cq;
      float v = X[(size_t)(cbase + c) * N_ + n0 + nl];
      float r = fminf(fmaxf(rintf(v), 0.f), 8.f);
      s[c * 65 + nl] = (unsigned short)(__float_as_uint(r) >> 16);
    }
    __syncthreads();
#pragma unroll 2
    for (int j = 0; j < 2; ++j) {
      int ccl = j * 4 + cq;
      int cc = cb * 8 + ccl;
      unsigned short v8[8];
#pragma unroll
      for (int d = 0; d < 8; ++d) v8[d] = s[(ccl * 8 + d) * 65 + nl];
      int n = n0 + nl;
      uint4 pk;
      pk.x = (unsigned)v8[0] | ((unsigned)v8[1] << 16);
      pk.y = (unsigned)v8[2] | ((unsigned)v8[3] << 16);
      pk.z = (unsigned)v8[4] | ((unsigned)v8[5] << 16);
      pk.w = (unsigned)v8[6] | ((unsigned)v8[7] << 16);
      *(uint4*)&dstb[(size_t)(n >> 4) * 4096 + cc * 128 + (n & 15) * 8] = pk;
    }
    __syncthreads();
  }
}

// ---------------------------------------------------------------------------
// K2: fused q/k/v GEMM. One block per (ntile, tb); B tile (64 KB) LDS-resident,
// A (weight images) double-buffered 8 KB stages, 144 stages = 6 z * 3 sp * 8 ks.
// ---------------------------------------------------------------------------
__global__ __launch_bounds__(256) void qkv_fused(
    const unsigned short* __restrict__ xsb, const unsigned short* __restrict__ wsp,
    const float* __restrict__ bnw,
    uint8_t* __restrict__ qs, uint8_t* __restrict__ ks_, uint8_t* __restrict__ vs) {
  __shared__ __align__(16) char smem[81920];   // 64KB B + 2x8KB A (no LDS ptr arrays!)
  char* smB = smem;
  const int t = threadIdx.x;
  const int L = t & 63, w = t >> 6;
  const int wrow = w >> 1, wcol = w & 1;
  const int n0 = blockIdx.x * 128;
  const int tb = blockIdx.y;

  // preload resident B (16 chunks of 4KB)
  const char* Bb = (const char*)(xsb + (size_t)tb * XSB_TB) + (size_t)blockIdx.x * 65536;
#pragma unroll
  for (int i = 0; i < 16; ++i)
    glds16(Bb + (i * 256 + t) * 16, smB + (i * 256 + t) * 16);

  const char* Wb = (const char*)wsp;
  // stage s: z = s/24, sp = (s%24)/8, ks = s%8; A image 8KB each
  {
    char* dst = smem + 65536;
    glds16(Wb + t * 16, dst + t * 16);
    glds16(Wb + t * 16 + 4096, dst + t * 16 + 4096);
  }

  f32x4 acc[4][4];
#pragma unroll
  for (int i = 0; i < 4; ++i)
#pragma unroll
    for (int j = 0; j < 4; ++j) acc[i][j] = (f32x4){0.f, 0.f, 0.f, 0.f};

#pragma unroll 1
  for (int s = 0; s < 144; ++s) {
    __syncthreads();
    if (s + 1 < 144) {
      int s1 = s + 1;
      int z1 = s1 / 24, r1 = s1 % 24;
      int conv1 = z1 >> 1, rt1 = z1 & 1, sp1 = r1 >> 3, ks1 = r1 & 7;
      const char* A = Wb + ((size_t)((conv1 * 3 + sp1) * 2 + rt1) * 8 + ks1) * 8192;
      char* dst = smem + 65536 + (s1 & 1) * 8192;
      glds16(A + t * 16, dst + t * 16);
      glds16(A + t * 16 + 4096, dst + t * 16 + 4096);
    }
    const char* Ac = smem + 65536 + (s & 1) * 8192;
    const int ks = s & 7;
    bf16x8 af[4], bfr[4];
#pragma unroll
    for (int i = 0; i < 4; ++i) {
      af[i] = *(const bf16x8*)(Ac + (wrow * 4 + i) * 1024 + L * 16);
      bfr[i] = *(const bf16x8*)(smB + (wcol * 4 + i) * 8192 + ks * 1024 + L * 16);
    }
#pragma unroll
    for (int i = 0; i < 4; ++i)
#pragma unroll
      for (int j = 0; j < 4; ++j)
        acc[i][j] = __builtin_amdgcn_mfma_f32_16x16x32_bf16(af[i], bfr[j], acc[i][j], 0, 0, 0);

    if ((s % 24) == 23) {
      // epilogue for z = s/24
      int z = s / 24, conv = z >> 1, rt = z & 1;
      uint8_t* outp = (conv == 0 ? qs : (conv == 1 ? ks_ : vs)) + (size_t)tb * TBC;
      const float* sbn = bnw + conv * 512;
      const int rbase = rt * 128;
#pragma unroll
      for (int i = 0; i < 4; ++i) {
        int co0 = rbase + wrow * 64 + i * 16 + ((L >> 4) << 2);
#pragma unroll
        for (int j = 0; j < 4; ++j) {
          int n = n0 + wcol * 64 + j * 16 + (L & 15);
          if (n < N_) {
#pragma unroll
            for (int r = 0; r < 4; ++r) {
              int co = co0 + r;
              float y = acc[i][j][r] * 0.125f;
              float tt = __fadd_rn(__fmul_rn(y, sbn[co]), sbn[256 + co]);
              float rr = fminf(fmaxf(rintf(tt), 0.f), 8.f);
              outp[(size_t)co * N_ + n] = (uint8_t)rr;
            }
          }
          acc[i][j] = (f32x4){0.f, 0.f, 0.f, 0.f};
        }
      }
    }
  }
}

// ---------------------------------------------------------------------------
// K3a: zero the kv accumulator
// ---------------------------------------------------------------------------
__global__ void zero_kv(int* __restrict__ kvg) {
  int i = blockIdx.x * 256 + threadIdx.x;
  ((int4*)kvg)[i] = make_int4(0, 0, 0, 0);   // 262144 ints = 65536 int4
}

// ---------------------------------------------------------------------------
// K3b: partial kv = k^T v over an n-chunk, exact i32 atomics. grid (8,32,PARTS)
// ---------------------------------------------------------------------------
__global__ __launch_bounds__(256) void attn_kv(
    const uint8_t* __restrict__ ks, const uint8_t* __restrict__ vs,
    int* __restrict__ kvg) {
  const int h = blockIdx.x, tb = blockIdx.y, part = blockIdx.z;
  const int tid = threadIdx.x;
  __shared__ unsigned sk[32][64];
  __shared__ unsigned sv[32][64];
  const uint8_t* K = ks + (size_t)tb * TBC + h * 32 * N_;
  const uint8_t* V = vs + (size_t)tb * TBC + h * 32 * N_;
  const int d0 = (tid >> 4) * 2;
  const int e0 = (tid & 15) * 2;
  const int pbase = part * CHUNK;
  const int pend = pbase + CHUNK;
  int acc[2][2] = {};

  for (int nt = 0; nt < 4; ++nt) {     // slabs of 256
    int n0 = pbase + nt * 256;
    if (n0 >= pend) break;
    if (nt) __syncthreads();
#pragma unroll
    for (int i = 0; i < 8; ++i) {
      int idx = tid + i * 256;
      int d = idx >> 6, w2 = idx & 63;
      int n = n0 + w2 * 4;
      unsigned kw_ = 0, vw_ = 0;
      if (n < pend) {
        kw_ = *(const unsigned*)&K[d * N_ + n];
        vw_ = *(const unsigned*)&V[d * N_ + n];
      }
      sk[d][w2] = kw_;
      sv[d][w2] = vw_;
    }
    __syncthreads();
#pragma unroll
    for (int w2 = 0; w2 < 64; w2 += 4) {
      uint4 ka = *(const uint4*)&sk[d0][w2];
      uint4 kb = *(const uint4*)&sk[d0 + 1][w2];
      uint4 va = *(const uint4*)&sv[e0][w2];
      uint4 vb = *(const uint4*)&sv[e0 + 1][w2];
      unsigned kwds[2][4] = {{ka.x, ka.y, ka.z, ka.w}, {kb.x, kb.y, kb.z, kb.w}};
      unsigned vwds[2][4] = {{va.x, va.y, va.z, va.w}, {vb.x, vb.y, vb.z, vb.w}};
#pragma unroll
      for (int di = 0; di < 2; ++di)
#pragma unroll
        for (int ej = 0; ej < 2; ++ej)
#pragma unroll
          for (int c = 0; c < 4; ++c)
            acc[di][ej] = dot4(kwds[di][c], vwds[ej][c], acc[di][ej]);
    }
  }
  int* dst = kvg + ((size_t)(tb * 8 + h)) * 1024;
  atomicAdd(&dst[d0 * 32 + e0], acc[0][0]);
  atomicAdd(&dst[d0 * 32 + e0 + 1], acc[0][1]);
  atomicAdd(&dst[(d0 + 1) * 32 + e0], acc[1][0]);
  atomicAdd(&dst[(d0 + 1) * 32 + e0 + 1], acc[1][1]);
}

// ---------------------------------------------------------------------------
// K3c: o = quant(q . kv * scale) over an n-chunk. grid (8,32,PARTS)
// ---------------------------------------------------------------------------
__global__ __launch_bounds__(256) void attn_o(
    const uint8_t* __restrict__ qs, const int* __restrict__ kvg,
    uint8_t* __restrict__ os_) {
  const int h = blockIdx.x, tb = blockIdx.y, part = blockIdx.z;
  const int tid = threadIdx.x;
  __shared__ uint8_t sq[256][48];
  const uint8_t* Q = qs + (size_t)tb * TBC + h * 32 * N_;
  uint8_t* O = os_ + (size_t)tb * TBC + h * 32 * N_;
  const int e = tid & 31;
  const int g = tid >> 5;
  const int* kvp = kvg + ((size_t)(tb * 8 + h)) * 1024;
  int kvcol[32];
#pragma unroll
  for (int d = 0; d < 32; ++d) kvcol[d] = kvp[d * 32 + e];

  const float cscale = (float)(0.3535533905932738 / 512.0);
  const int pbase = part * CHUNK;
  const int pend = pbase + CHUNK;

  for (int nt = 0; nt < 4; ++nt) {
    int n0 = pbase + nt * 256;
    if (n0 >= pend) break;
    if (nt) __syncthreads();
#pragma unroll
    for (int i = 0; i < 8; ++i) {
      int idx = tid + i * 256;
      int d = idx >> 6, w2 = idx & 63;
      int n = n0 + w2 * 4;
      unsigned qw_ = 0;
      if (n < pend) qw_ = *(const unsigned*)&Q[d * N_ + n];
      sq[w2 * 4 + 0][d] = (uint8_t)(qw_ & 255u);
      sq[w2 * 4 + 1][d] = (uint8_t)((qw_ >> 8) & 255u);
      sq[w2 * 4 + 2][d] = (uint8_t)((qw_ >> 16) & 255u);
      sq[w2 * 4 + 3][d] = (uint8_t)(qw_ >> 24);
    }
    __syncthreads();
#pragma unroll
    for (int s8 = 0; s8 < 8; ++s8) {
      int nl = (s8 * 8 + g) * 4;
      int n = n0 + nl;
      if (n >= pend) continue;
      uint8_t ob[4];
#pragma unroll
      for (int jn = 0; jn < 4; ++jn) {
        const uint8_t* qrow = &sq[nl + jn][0];
        uint4 qa = *(const uint4*)&qrow[0];
        uint4 qb = *(const uint4*)&qrow[16];
        unsigned qq[8] = {qa.x, qa.y, qa.z, qa.w, qb.x, qb.y, qb.z, qb.w};
        int o = 0;
#pragma unroll
        for (int qi = 0; qi < 8; ++qi)
#pragma unroll
          for (int m = 0; m < 4; ++m)
            o += (int)((qq[qi] >> (8 * m)) & 255u) * kvcol[qi * 4 + m];
        float of = (float)o * cscale;
        float r = fminf(fmaxf(rintf(of), 0.f), 8.f);
        ob[jn] = (uint8_t)r;
      }
      *(uchar4*)&O[e * N_ + n] = make_uchar4(ob[0], ob[1], ob[2], ob[3]);
    }
  }
}

// ---------------------------------------------------------------------------
// K4: out = BN(pw @ os/8) via bf16 MFMA
// ---------------------------------------------------------------------------
__global__ __launch_bounds__(256) void out_mfma(
    const uint8_t* __restrict__ os_, const unsigned short* __restrict__ wsp,
    const float* __restrict__ bnw, float* __restrict__ out) {
  __shared__ __align__(16) char smem[16384];
  char* smA = smem;
  char* smB = smem + 8192;
  const int t = threadIdx.x;
  const int L = t & 63, w = t >> 6;
  const int wrow = w >> 1, wcol = w & 1;
  const int n0 = blockIdx.x * 128;
  const int tb = blockIdx.y;
  const int rt = blockIdx.z;
  const uint8_t* X = os_ + (size_t)tb * TBC;

  f32x4 acc[4][4];
#pragma unroll
  for (int i = 0; i < 4; ++i)
#pragma unroll
    for (int j = 0; j < 4; ++j) acc[i][j] = (f32x4){0.f, 0.f, 0.f, 0.f};

  for (int sp = 0; sp < 3; ++sp) {
    const char* Asp = (const char*)wsp + ((size_t)(9 + sp) * 16 + rt * 8) * 8192;
#pragma unroll 1
    for (int ks2 = 0; ks2 < 8; ++ks2) {
      __syncthreads();
      const char* Ak = Asp + ks2 * 8192;
      glds16(Ak + t * 16, smA + t * 16);
      glds16(Ak + t * 16 + 4096, smA + t * 16 + 4096);
#pragma unroll
      for (int i2 = 0; i2 < 4; ++i2) {
        int id = t + 256 * i2;
        int cl = id >> 5, nq = id & 31;
        int n = n0 + nq * 4;
        unsigned wv = 0;
        if (n < N_) wv = *(const unsigned*)&X[(size_t)(ks2 * 32 + cl) * N_ + n];
        int ntile = nq >> 2, cc = cl >> 3, jj = cl & 7;
        unsigned short* dsts = (unsigned short*)(smB + ntile * 1024 + cc * 256 + jj * 2);
#pragma unroll
        for (int dd = 0; dd < 4; ++dd) {
          int d = ((nq >> 2) + dd) & 3;
          float f = (float)((wv >> (8 * d)) & 255u);
          dsts[((nq & 3) * 4 + d) * 8] = (unsigned short)(__float_as_uint(f) >> 16);
        }
      }
      __syncthreads();
      bf16x8 af[4], bfr[4];
#pragma unroll
      for (int i = 0; i < 4; ++i) {
        af[i] = *(const bf16x8*)(smA + (wrow * 4 + i) * 1024 + L * 16);
        bfr[i] = *(const bf16x8*)(smB + (wcol * 4 + i) * 1024 + L * 16);
      }
#pragma unroll
      for (int i = 0; i < 4; ++i)
#pragma unroll
        for (int j = 0; j < 4; ++j)
          acc[i][j] = __builtin_amdgcn_mfma_f32_16x16x32_bf16(af[i], bfr[j], acc[i][j], 0, 0, 0);
    }
  }

  float* O = out + (size_t)tb * TBC;
  const float* sbn = bnw + 3 * 512;
  const int rbase = rt * 128;
#pragma unroll
  for (int i = 0; i < 4; ++i) {
    int co0 = rbase + wrow * 64 + i * 16 + ((L >> 4) << 2);
#pragma unroll
    for (int j = 0; j < 4; ++j) {
      int n = n0 + wcol * 64 + j * 16 + (L & 15);
      if (n < N_) {
#pragma unroll
        for (int r = 0; r < 4; ++r) {
          int co = co0 + r;
          float y = acc[i][j][r] * 0.125f;
          O[(size_t)co * N_ + n] = __fadd_rn(__fmul_rn(y, sbn[co]), sbn[256 + co]);
        }
      }
    }
  }
}

// ---------------------------------------------------------------------------
extern "C" void kernel_launch(void* const* d_in, const int* in_sizes, int n_in,
                              void* d_out, int out_size, void* d_ws, size_t ws_size,
                              hipStream_t stream) {
  const float* x   = (const float*)d_in[0];
  const float* qw  = (const float*)d_in[1];
  const float* qbn = (const float*)d_in[2];
  const float* kw  = (const float*)d_in[3];
  const float* kbn = (const float*)d_in[4];
  const float* vw  = (const float*)d_in[5];
  const float* vbn = (const float*)d_in[6];
  const float* pw  = (const float*)d_in[7];
  const float* pbn = (const float*)d_in[8];
  float* out = (float*)d_out;

  uint8_t* ws = (uint8_t*)d_ws;
  float* bnw           = (float*)ws;                         // 8 KB
  unsigned short* wsp  = (unsigned short*)(ws + 8192);       // 1.5 MB
  unsigned short* xsb  = (unsigned short*)(ws + 1581056);    // 52.4 MB blocked spikes
  uint8_t* qsp = ws + 54009856;
  uint8_t* ksp = qsp + ACT_SZ;
  uint8_t* vsp = ksp + ACT_SZ;                               // ends at 131,080,192
  uint8_t* osp = (uint8_t*)xsb;                              // alias: xsb dead after qkv
  int* kvg = (int*)((uint8_t*)xsb + 26000000);               // alias: beyond osp's 25.7MB

  bn_prep<<<1, 256, 0, stream>>>(qbn, kbn, vbn, pbn, bnw);
  wprep<<<dim3(256, 4), 256, 0, stream>>>(qw, kw, vw, pw, wsp);
  quant_x_t<<<dim3(49, 32), 256, 0, stream>>>(x, xsb);
  qkv_fused<<<dim3(25, 32), 256, 0, stream>>>(xsb, wsp, bnw, qsp, ksp, vsp);
  zero_kv<<<256, 256, 0, stream>>>(kvg);
  attn_kv<<<dim3(8, 32, PARTS), 256, 0, stream>>>(ksp, vsp, kvg);
  attn_o<<<dim3(8, 32, PARTS), 256, 0, stream>>>(qsp, kvg, osp);
  out_mfma<<<dim3(25, 32, 2), 256, 0, stream>>>(osp, wsp, bnw, out);
}

// Round 5
// 557.545 us; speedup vs baseline: 1.2964x; 1.2964x over previous
//
#include <hip/hip_runtime.h>
#include <stdint.h>

#define TB_ 32
#define C_ 256
#define N_ 3136
#define TBC (C_ * N_)            // 802816 elems per (t,b) per 256-ch tensor
#define ACT_SZ (TB_ * TBC)       // 25690112
#define XSB_TB 819200            // u16 elems per tb in blocked layout (200 groups * 4096)
#define PARTS 4
#define CHUNK 784                // 3136/4, multiple of 16

typedef __attribute__((ext_vector_type(8))) short bf16x8;
typedef __attribute__((ext_vector_type(4))) float f32x4;

__device__ __forceinline__ void glds16(const void* gp, void* lp) {
  __builtin_amdgcn_global_load_lds(
      (const __attribute__((address_space(1))) unsigned int*)gp,
      (__attribute__((address_space(3))) unsigned int*)lp, 16, 0, 0);
}

__device__ __forceinline__ unsigned short bf16rn(float f, float* val) {
  unsigned b = __float_as_uint(f);
  unsigned r = (b + 0x7fffu + ((b >> 16) & 1u)) >> 16;
  *val = __uint_as_float(r << 16);
  return (unsigned short)r;
}

__device__ __forceinline__ int dot4u(unsigned a, unsigned b, int c) {
  c += (int)(a & 255u)         * (int)(b & 255u);
  c += (int)((a >> 8) & 255u)  * (int)((b >> 8) & 255u);
  c += (int)((a >> 16) & 255u) * (int)((b >> 16) & 255u);
  c += (int)(a >> 24)          * (int)(b >> 24);
  return c;
}

// bytes are 0..8 -> positive as signed i8, sdot4 is exact here
__device__ __forceinline__ int dot4(unsigned a, unsigned b, int c) {
#if defined(__has_builtin)
#if __has_builtin(__builtin_amdgcn_sdot4)
  return __builtin_amdgcn_sdot4((int)a, (int)b, c, false);
#else
  return dot4u(a, b, c);
#endif
#else
  return dot4u(a, b, c);
#endif
}

// ---------------------------------------------------------------------------
// K0: fold BN params
// ---------------------------------------------------------------------------
__global__ void bn_prep(const float* __restrict__ qbn, const float* __restrict__ kbn,
                        const float* __restrict__ vbn, const float* __restrict__ pbn,
                        float* __restrict__ bnw) {
  int c = threadIdx.x;
  const float* ps[4] = {qbn, kbn, vbn, pbn};
#pragma unroll
  for (int i = 0; i < 4; ++i) {
    const float* p = ps[i];
    float g = p[c], be = p[256 + c], mn = p[512 + c], vr = p[768 + c];
    float s = g / sqrtf(vr + 1e-5f);
    float b = __fsub_rn(be, __fmul_rn(mn, s));
    bnw[i * 512 + c] = s;
    bnw[i * 512 + 256 + c] = b;
  }
}

// ---------------------------------------------------------------------------
// K0b: exact 3-term bf16 split of fp32 weights into MFMA A-fragment images
// ---------------------------------------------------------------------------
__global__ void wprep(const float* __restrict__ qw, const float* __restrict__ kw,
                      const float* __restrict__ vw, const float* __restrict__ pw,
                      unsigned short* __restrict__ wsp) {
  const float* Ws[4] = {qw, kw, vw, pw};
  int m = blockIdx.y, co = blockIdx.x, k = threadIdx.x;
  float w = Ws[m][co * 256 + k];
  float h1, h2, h3r;
  unsigned short u1 = bf16rn(w, &h1);
  float r1 = __fsub_rn(w, h1);
  unsigned short u2 = bf16rn(r1, &h2);
  float r2 = __fsub_rn(r1, h2);
  unsigned short u3 = bf16rn(r2, &h3r);   // exact: r2 has <=8 significant bits
  int rt = co >> 7, ks = k >> 5;
  int lane = (co & 15) + 16 * ((k >> 3) & 3);
  unsigned short us[3] = {u1, u2, u3};
#pragma unroll
  for (int sp = 0; sp < 3; ++sp) {
    size_t off = (size_t)((((m * 3 + sp) * 2 + rt) * 8 + ks)) * 4096 + lane * 8 + (k & 7);
    wsp[off] = us[sp];
  }
}

// ---------------------------------------------------------------------------
// K1: x -> spikes (bf16, exact 0..8) in blocked B-fragment layout
// ---------------------------------------------------------------------------
__global__ __launch_bounds__(256) void quant_x_t(const float* __restrict__ x,
                                                 unsigned short* __restrict__ xsb) {
  __shared__ unsigned short s[64 * 65];
  const int t = threadIdx.x;
  const int n0 = blockIdx.x * 64;
  const int tb = blockIdx.y;
  const float* X = x + (size_t)tb * TBC;
  const int nl = t & 63, cq = t >> 6;

  unsigned short* dstb = xsb + (size_t)tb * XSB_TB;
  for (int cb = 0; cb < 4; ++cb) {
    int cbase = cb * 64;
#pragma unroll 4
    for (int i = 0; i < 16; ++i) {
      int c = i * 4 + cq;
      float v = X[(size_t)(cbase + c) * N_ + n0 + nl];
      float r = fminf(fmaxf(rintf(v), 0.f), 8.f);
      s[c * 65 + nl] = (unsigned short)(__float_as_uint(r) >> 16);
    }
    __syncthreads();
#pragma unroll 2
    for (int j = 0; j < 2; ++j) {
      int ccl = j * 4 + cq;
      int cc = cb * 8 + ccl;
      unsigned short v8[8];
#pragma unroll
      for (int d = 0; d < 8; ++d) v8[d] = s[(ccl * 8 + d) * 65 + nl];
      int n = n0 + nl;
      uint4 pk;
      pk.x = (unsigned)v8[0] | ((unsigned)v8[1] << 16);
      pk.y = (unsigned)v8[2] | ((unsigned)v8[3] << 16);
      pk.z = (unsigned)v8[4] | ((unsigned)v8[5] << 16);
      pk.w = (unsigned)v8[6] | ((unsigned)v8[7] << 16);
      *(uint4*)&dstb[(size_t)(n >> 4) * 4096 + cc * 128 + (n & 15) * 8] = pk;
    }
    __syncthreads();
  }
}

// ---------------------------------------------------------------------------
// K2: q/k/v GEMM, round-2 structure (16 KB LDS, high occupancy) with an
// XCD-aware 1D swizzle: b = oct*48 + s*8 + gl -> all 6 z-siblings of a
// (ntile,tb) group share b%8 (same XCD) within a 48-block window, so the
// 64 KB B slice is HBM-fetched once and L2-served 18x. Numerically
// identical to round-2 qkv_mfma (same accumulation order).
// ---------------------------------------------------------------------------
__global__ __launch_bounds__(256) void qkv_mfma_sw(
    const unsigned short* __restrict__ xsb, const unsigned short* __restrict__ wsp,
    const float* __restrict__ bnw,
    uint8_t* __restrict__ qs, uint8_t* __restrict__ ks_, uint8_t* __restrict__ vs) {
  __shared__ __align__(16) char smem[16384];
  char* smA = smem;
  char* smB = smem + 8192;
  const int t = threadIdx.x;
  const int L = t & 63, w = t >> 6;
  const int wrow = w >> 1, wcol = w & 1;
  const int b = blockIdx.x;
  const int oct = b / 48, rem = b % 48;
  const int s = rem >> 3, gl = rem & 7;
  const int g = oct * 8 + gl;
  const int ntile = g % 25, tb = g / 25;
  const int conv = s >> 1, rt = s & 1;
  const int n0 = ntile * 128;

  const char* Bb = (const char*)(xsb + (size_t)tb * XSB_TB) + (size_t)ntile * 65536;

  f32x4 acc[4][4];
#pragma unroll
  for (int i = 0; i < 4; ++i)
#pragma unroll
    for (int j = 0; j < 4; ++j) acc[i][j] = (f32x4){0.f, 0.f, 0.f, 0.f};

  for (int sp = 0; sp < 3; ++sp) {
    const char* Asp = (const char*)wsp + ((size_t)(conv * 3 + sp) * 16 + rt * 8) * 8192;
#pragma unroll 1
    for (int ks2 = 0; ks2 < 8; ++ks2) {
      __syncthreads();
      const char* Ak = Asp + ks2 * 8192;
      glds16(Ak + t * 16, smA + t * 16);
      glds16(Ak + t * 16 + 4096, smA + t * 16 + 4096);
      const char* Bk = Bb + ks2 * 1024;
      glds16(Bk + (size_t)w * 8192 + L * 16, smB + t * 16);
      glds16(Bk + (size_t)(w + 4) * 8192 + L * 16, smB + t * 16 + 4096);
      __syncthreads();
      bf16x8 af[4], bfr[4];
#pragma unroll
      for (int i = 0; i < 4; ++i) {
        af[i] = *(const bf16x8*)(smA + (wrow * 4 + i) * 1024 + L * 16);
        bfr[i] = *(const bf16x8*)(smB + (wcol * 4 + i) * 1024 + L * 16);
      }
#pragma unroll
      for (int i = 0; i < 4; ++i)
#pragma unroll
        for (int j = 0; j < 4; ++j)
          acc[i][j] = __builtin_amdgcn_mfma_f32_16x16x32_bf16(af[i], bfr[j], acc[i][j], 0, 0, 0);
    }
  }

  uint8_t* outp = (conv == 0 ? qs : (conv == 1 ? ks_ : vs)) + (size_t)tb * TBC;
  const float* sbn = bnw + conv * 512;
  const int rbase = rt * 128;
#pragma unroll
  for (int i = 0; i < 4; ++i) {
    int co0 = rbase + wrow * 64 + i * 16 + ((L >> 4) << 2);
#pragma unroll
    for (int j = 0; j < 4; ++j) {
      int n = n0 + wcol * 64 + j * 16 + (L & 15);
      if (n < N_) {
#pragma unroll
        for (int r = 0; r < 4; ++r) {
          int co = co0 + r;
          float y = acc[i][j][r] * 0.125f;
          float tt = __fadd_rn(__fmul_rn(y, sbn[co]), sbn[256 + co]);
          float rr = fminf(fmaxf(rintf(tt), 0.f), 8.f);
          outp[(size_t)co * N_ + n] = (uint8_t)rr;
        }
      }
    }
  }
}

// ---------------------------------------------------------------------------
// K3a: zero the kv accumulators living in osb's padding groups (196..199/tb)
// ---------------------------------------------------------------------------
__global__ void zero_kv(unsigned short* __restrict__ osb) {
  int tb = blockIdx.x;
  int4* p = (int4*)(osb + (size_t)tb * XSB_TB + 802816);
  for (int i = threadIdx.x; i < 2048; i += 256) p[i] = make_int4(0, 0, 0, 0);
}

// ---------------------------------------------------------------------------
// K3b: partial kv = k^T v over an n-chunk, exact i32 atomics. grid (8,32,PARTS)
// kv scratch lives in osb padding (only feeds discarded MFMA columns later).
// ---------------------------------------------------------------------------
__global__ __launch_bounds__(256) void attn_kv(
    const uint8_t* __restrict__ ks, const uint8_t* __restrict__ vs,
    unsigned short* __restrict__ osb) {
  const int h = blockIdx.x, tb = blockIdx.y, part = blockIdx.z;
  const int tid = threadIdx.x;
  __shared__ unsigned sk[32][64];
  __shared__ unsigned sv[32][64];
  const uint8_t* K = ks + (size_t)tb * TBC + h * 32 * N_;
  const uint8_t* V = vs + (size_t)tb * TBC + h * 32 * N_;
  const int d0 = (tid >> 4) * 2;
  const int e0 = (tid & 15) * 2;
  const int pbase = part * CHUNK;
  const int pend = pbase + CHUNK;
  int acc[2][2] = {};

  for (int nt = 0; nt < 4; ++nt) {
    int n0 = pbase + nt * 256;
    if (n0 >= pend) break;
    if (nt) __syncthreads();
#pragma unroll
    for (int i = 0; i < 8; ++i) {
      int idx = tid + i * 256;
      int d = idx >> 6, w2 = idx & 63;
      int n = n0 + w2 * 4;
      unsigned kw_ = 0, vw_ = 0;
      if (n < pend) {
        kw_ = *(const unsigned*)&K[d * N_ + n];
        vw_ = *(const unsigned*)&V[d * N_ + n];
      }
      sk[d][w2] = kw_;
      sv[d][w2] = vw_;
    }
    __syncthreads();
#pragma unroll
    for (int w2 = 0; w2 < 64; w2 += 4) {
      uint4 ka = *(const uint4*)&sk[d0][w2];
      uint4 kb = *(const uint4*)&sk[d0 + 1][w2];
      uint4 va = *(const uint4*)&sv[e0][w2];
      uint4 vb = *(const uint4*)&sv[e0 + 1][w2];
      unsigned kwds[2][4] = {{ka.x, ka.y, ka.z, ka.w}, {kb.x, kb.y, kb.z, kb.w}};
      unsigned vwds[2][4] = {{va.x, va.y, va.z, va.w}, {vb.x, vb.y, vb.z, vb.w}};
#pragma unroll
      for (int di = 0; di < 2; ++di)
#pragma unroll
        for (int ej = 0; ej < 2; ++ej)
#pragma unroll
          for (int c = 0; c < 4; ++c)
            acc[di][ej] = dot4(kwds[di][c], vwds[ej][c], acc[di][ej]);
    }
  }
  int* dst = (int*)(osb + (size_t)tb * XSB_TB + 802816) + h * 1024;
  atomicAdd(&dst[d0 * 32 + e0], acc[0][0]);
  atomicAdd(&dst[d0 * 32 + e0 + 1], acc[0][1]);
  atomicAdd(&dst[(d0 + 1) * 32 + e0], acc[1][0]);
  atomicAdd(&dst[(d0 + 1) * 32 + e0 + 1], acc[1][1]);
}

// ---------------------------------------------------------------------------
// K3c: o = quant(q . kv * scale), written directly as bf16 spikes in the
// blocked B-fragment layout (same bit patterns round-2's unpack produced).
// grid (8,32,PARTS)
// ---------------------------------------------------------------------------
__global__ __launch_bounds__(256) void attn_o(
    const uint8_t* __restrict__ qs, unsigned short* __restrict__ osb) {
  const int h = blockIdx.x, tb = blockIdx.y, part = blockIdx.z;
  const int tid = threadIdx.x;
  __shared__ uint8_t sq[256][48];
  const uint8_t* Q = qs + (size_t)tb * TBC + h * 32 * N_;
  unsigned short* osb_tb = osb + (size_t)tb * XSB_TB;
  const int e = tid & 31;
  const int g2 = tid >> 5;
  const int c = h * 32 + e;
  const int cc = c >> 3, c7 = c & 7;
  const int* kvp = (const int*)(osb + (size_t)tb * XSB_TB + 802816) + h * 1024;
  int kvcol[32];
#pragma unroll
  for (int d = 0; d < 32; ++d) kvcol[d] = kvp[d * 32 + e];

  const float cscale = (float)(0.3535533905932738 / 512.0);
  const int pbase = part * CHUNK;
  const int pend = pbase + CHUNK;

  for (int nt = 0; nt < 4; ++nt) {
    int n0 = pbase + nt * 256;
    if (n0 >= pend) break;
    if (nt) __syncthreads();
#pragma unroll
    for (int i = 0; i < 8; ++i) {
      int idx = tid + i * 256;
      int d = idx >> 6, w2 = idx & 63;
      int n = n0 + w2 * 4;
      unsigned qw_ = 0;
      if (n < pend) qw_ = *(const unsigned*)&Q[d * N_ + n];
      sq[w2 * 4 + 0][d] = (uint8_t)(qw_ & 255u);
      sq[w2 * 4 + 1][d] = (uint8_t)((qw_ >> 8) & 255u);
      sq[w2 * 4 + 2][d] = (uint8_t)((qw_ >> 16) & 255u);
      sq[w2 * 4 + 3][d] = (uint8_t)(qw_ >> 24);
    }
    __syncthreads();
#pragma unroll
    for (int s8 = 0; s8 < 8; ++s8) {
      int nl = (s8 * 8 + g2) * 4;
      int n = n0 + nl;
      if (n >= pend) continue;
      size_t gbase = (size_t)(n >> 4) * 4096 + cc * 128 + c7;
#pragma unroll
      for (int jn = 0; jn < 4; ++jn) {
        const uint8_t* qrow = &sq[nl + jn][0];
        uint4 qa = *(const uint4*)&qrow[0];
        uint4 qb = *(const uint4*)&qrow[16];
        unsigned qq[8] = {qa.x, qa.y, qa.z, qa.w, qb.x, qb.y, qb.z, qb.w};
        int o = 0;
#pragma unroll
        for (int qi = 0; qi < 8; ++qi)
#pragma unroll
          for (int m = 0; m < 4; ++m)
            o += (int)((qq[qi] >> (8 * m)) & 255u) * kvcol[qi * 4 + m];
        float of = (float)o * cscale;
        float r = fminf(fmaxf(rintf(of), 0.f), 8.f);
        osb_tb[gbase + ((n & 15) + jn) * 8] = (unsigned short)(__float_as_uint(r) >> 16);
      }
    }
  }
}

// ---------------------------------------------------------------------------
// K4: out = BN(pw @ os/8) via bf16 MFMA; B staged with glds16 from the
// blocked osb layout (bitwise-identical LDS image to round-2's unpack).
// Same XCD swizzle: b = oct*16 + s*8 + gl, 2 rt-siblings share b%8.
// ---------------------------------------------------------------------------
__global__ __launch_bounds__(256) void out_mfma_sw(
    const unsigned short* __restrict__ osb, const unsigned short* __restrict__ wsp,
    const float* __restrict__ bnw, float* __restrict__ out) {
  __shared__ __align__(16) char smem[16384];
  char* smA = smem;
  char* smB = smem + 8192;
  const int t = threadIdx.x;
  const int L = t & 63, w = t >> 6;
  const int wrow = w >> 1, wcol = w & 1;
  const int b = blockIdx.x;
  const int oct = b / 16, rem = b % 16;
  const int rt = rem >> 3, gl = rem & 7;
  const int g = oct * 8 + gl;
  const int ntile = g % 25, tb = g / 25;
  const int n0 = ntile * 128;
  const char* Bb = (const char*)(osb + (size_t)tb * XSB_TB) + (size_t)ntile * 65536;

  f32x4 acc[4][4];
#pragma unroll
  for (int i = 0; i < 4; ++i)
#pragma unroll
    for (int j = 0; j < 4; ++j) acc[i][j] = (f32x4){0.f, 0.f, 0.f, 0.f};

  for (int sp = 0; sp < 3; ++sp) {
    const char* Asp = (const char*)wsp + ((size_t)(9 + sp) * 16 + rt * 8) * 8192;
#pragma unroll 1
    for (int ks2 = 0; ks2 < 8; ++ks2) {
      __syncthreads();
      const char* Ak = Asp + ks2 * 8192;
      glds16(Ak + t * 16, smA + t * 16);
      glds16(Ak + t * 16 + 4096, smA + t * 16 + 4096);
      const char* Bk = Bb + ks2 * 1024;
      glds16(Bk + (size_t)w * 8192 + L * 16, smB + t * 16);
      glds16(Bk + (size_t)(w + 4) * 8192 + L * 16, smB + t * 16 + 4096);
      __syncthreads();
      bf16x8 af[4], bfr[4];
#pragma unroll
      for (int i = 0; i < 4; ++i) {
        af[i] = *(const bf16x8*)(smA + (wrow * 4 + i) * 1024 + L * 16);
        bfr[i] = *(const bf16x8*)(smB + (wcol * 4 + i) * 1024 + L * 16);
      }
#pragma unroll
      for (int i = 0; i < 4; ++i)
#pragma unroll
        for (int j = 0; j < 4; ++j)
          acc[i][j] = __builtin_amdgcn_mfma_f32_16x16x32_bf16(af[i], bfr[j], acc[i][j], 0, 0, 0);
    }
  }

  float* O = out + (size_t)tb * TBC;
  const float* sbn = bnw + 3 * 512;
  const int rbase = rt * 128;
#pragma unroll
  for (int i = 0; i < 4; ++i) {
    int co0 = rbase + wrow * 64 + i * 16 + ((L >> 4) << 2);
#pragma unroll
    for (int j = 0; j < 4; ++j) {
      int n = n0 + wcol * 64 + j * 16 + (L & 15);
      if (n < N_) {
#pragma unroll
        for (int r = 0; r < 4; ++r) {
          int co = co0 + r;
          float y = acc[i][j][r] * 0.125f;
          O[(size_t)co * N_ + n] = __fadd_rn(__fmul_rn(y, sbn[co]), sbn[256 + co]);
        }
      }
    }
  }
}

// ---------------------------------------------------------------------------
extern "C" void kernel_launch(void* const* d_in, const int* in_sizes, int n_in,
                              void* d_out, int out_size, void* d_ws, size_t ws_size,
                              hipStream_t stream) {
  const float* x   = (const float*)d_in[0];
  const float* qw  = (const float*)d_in[1];
  const float* qbn = (const float*)d_in[2];
  const float* kw  = (const float*)d_in[3];
  const float* kbn = (const float*)d_in[4];
  const float* vw  = (const float*)d_in[5];
  const float* vbn = (const float*)d_in[6];
  const float* pw  = (const float*)d_in[7];
  const float* pbn = (const float*)d_in[8];
  float* out = (float*)d_out;

  uint8_t* ws = (uint8_t*)d_ws;
  float* bnw           = (float*)ws;                         // 8 KB
  unsigned short* wsp  = (unsigned short*)(ws + 8192);       // 1.57 MB
  unsigned short* xsb  = (unsigned short*)(ws + 1581056);    // 52.4 MB blocked spikes
  uint8_t* qsp = ws + 54009856;
  uint8_t* ksp = qsp + ACT_SZ;
  uint8_t* vsp = ksp + ACT_SZ;                               // ends at 131,080,192
  unsigned short* osb = xsb;   // alias: xsb dead after qkv; osb (blocked o) + kv scratch in padding

  bn_prep<<<1, 256, 0, stream>>>(qbn, kbn, vbn, pbn, bnw);
  wprep<<<dim3(256, 4), 256, 0, stream>>>(qw, kw, vw, pw, wsp);
  quant_x_t<<<dim3(49, 32), 256, 0, stream>>>(x, xsb);
  qkv_mfma_sw<<<4800, 256, 0, stream>>>(xsb, wsp, bnw, qsp, ksp, vsp);
  zero_kv<<<32, 256, 0, stream>>>(osb);
  attn_kv<<<dim3(8, 32, PARTS), 256, 0, stream>>>(ksp, vsp, osb);
  attn_o<<<dim3(8, 32, PARTS), 256, 0, stream>>>(qsp, osb);
  out_mfma_sw<<<1600, 256, 0, stream>>>(osb, wsp, bnw, out);
}

// Round 6
// 527.495 us; speedup vs baseline: 1.3702x; 1.0570x over previous
//
#include <hip/hip_runtime.h>
#include <stdint.h>

#define TB_ 32
#define C_ 256
#define N_ 3136
#define TBC (C_ * N_)            // 802816 elems per (t,b) per 256-ch tensor
#define ACT_SZ (TB_ * TBC)       // 25690112
#define XSB_TB 819200            // u16 elems per tb in blocked layout (200 groups * 4096)
#define PARTS 7
#define CHUNK 448                // 3136/7, multiple of 16

typedef __attribute__((ext_vector_type(8))) short bf16x8;
typedef __attribute__((ext_vector_type(4))) float f32x4;

__device__ __forceinline__ void glds16(const void* gp, void* lp) {
  __builtin_amdgcn_global_load_lds(
      (const __attribute__((address_space(1))) unsigned int*)gp,
      (__attribute__((address_space(3))) unsigned int*)lp, 16, 0, 0);
}

__device__ __forceinline__ unsigned short bf16rn(float f, float* val) {
  unsigned b = __float_as_uint(f);
  unsigned r = (b + 0x7fffu + ((b >> 16) & 1u)) >> 16;
  *val = __uint_as_float(r << 16);
  return (unsigned short)r;
}

__device__ __forceinline__ int dot4u(unsigned a, unsigned b, int c) {
  c += (int)(a & 255u)         * (int)(b & 255u);
  c += (int)((a >> 8) & 255u)  * (int)((b >> 8) & 255u);
  c += (int)((a >> 16) & 255u) * (int)((b >> 16) & 255u);
  c += (int)(a >> 24)          * (int)(b >> 24);
  return c;
}

// bytes are 0..8 -> positive as signed i8, sdot4 is exact here
__device__ __forceinline__ int dot4(unsigned a, unsigned b, int c) {
#if defined(__has_builtin)
#if __has_builtin(__builtin_amdgcn_sdot4)
  return __builtin_amdgcn_sdot4((int)a, (int)b, c, false);
#else
  return dot4u(a, b, c);
#endif
#else
  return dot4u(a, b, c);
#endif
}

// ---------------------------------------------------------------------------
// K0: fold BN params
// ---------------------------------------------------------------------------
__global__ void bn_prep(const float* __restrict__ qbn, const float* __restrict__ kbn,
                        const float* __restrict__ vbn, const float* __restrict__ pbn,
                        float* __restrict__ bnw) {
  int c = threadIdx.x;
  const float* ps[4] = {qbn, kbn, vbn, pbn};
#pragma unroll
  for (int i = 0; i < 4; ++i) {
    const float* p = ps[i];
    float g = p[c], be = p[256 + c], mn = p[512 + c], vr = p[768 + c];
    float s = g / sqrtf(vr + 1e-5f);
    float b = __fsub_rn(be, __fmul_rn(mn, s));
    bnw[i * 512 + c] = s;
    bnw[i * 512 + 256 + c] = b;
  }
}

// ---------------------------------------------------------------------------
// K0b: exact 3-term bf16 split of fp32 weights into MFMA A-fragment images
// ---------------------------------------------------------------------------
__global__ void wprep(const float* __restrict__ qw, const float* __restrict__ kw,
                      const float* __restrict__ vw, const float* __restrict__ pw,
                      unsigned short* __restrict__ wsp) {
  const float* Ws[4] = {qw, kw, vw, pw};
  int m = blockIdx.y, co = blockIdx.x, k = threadIdx.x;
  float w = Ws[m][co * 256 + k];
  float h1, h2, h3r;
  unsigned short u1 = bf16rn(w, &h1);
  float r1 = __fsub_rn(w, h1);
  unsigned short u2 = bf16rn(r1, &h2);
  float r2 = __fsub_rn(r1, h2);
  unsigned short u3 = bf16rn(r2, &h3r);   // exact: r2 has <=8 significant bits
  int rt = co >> 7, ks = k >> 5;
  int lane = (co & 15) + 16 * ((k >> 3) & 3);
  unsigned short us[3] = {u1, u2, u3};
#pragma unroll
  for (int sp = 0; sp < 3; ++sp) {
    size_t off = (size_t)((((m * 3 + sp) * 2 + rt) * 8 + ks)) * 4096 + lane * 8 + (k & 7);
    wsp[off] = us[sp];
  }
}

// ---------------------------------------------------------------------------
// K1: x -> spikes (bf16, exact 0..8) in blocked B-fragment layout
// ---------------------------------------------------------------------------
__global__ __launch_bounds__(256) void quant_x_t(const float* __restrict__ x,
                                                 unsigned short* __restrict__ xsb) {
  __shared__ unsigned short s[64 * 65];
  const int t = threadIdx.x;
  const int n0 = blockIdx.x * 64;
  const int tb = blockIdx.y;
  const float* X = x + (size_t)tb * TBC;
  const int nl = t & 63, cq = t >> 6;

  unsigned short* dstb = xsb + (size_t)tb * XSB_TB;
  for (int cb = 0; cb < 4; ++cb) {
    int cbase = cb * 64;
#pragma unroll 4
    for (int i = 0; i < 16; ++i) {
      int c = i * 4 + cq;
      float v = X[(size_t)(cbase + c) * N_ + n0 + nl];
      float r = fminf(fmaxf(rintf(v), 0.f), 8.f);
      s[c * 65 + nl] = (unsigned short)(__float_as_uint(r) >> 16);
    }
    __syncthreads();
#pragma unroll 2
    for (int j = 0; j < 2; ++j) {
      int ccl = j * 4 + cq;
      int cc = cb * 8 + ccl;
      unsigned short v8[8];
#pragma unroll
      for (int d = 0; d < 8; ++d) v8[d] = s[(ccl * 8 + d) * 65 + nl];
      int n = n0 + nl;
      uint4 pk;
      pk.x = (unsigned)v8[0] | ((unsigned)v8[1] << 16);
      pk.y = (unsigned)v8[2] | ((unsigned)v8[3] << 16);
      pk.z = (unsigned)v8[4] | ((unsigned)v8[5] << 16);
      pk.w = (unsigned)v8[6] | ((unsigned)v8[7] << 16);
      *(uint4*)&dstb[(size_t)(n >> 4) * 4096 + cc * 128 + (n & 15) * 8] = pk;
    }
    __syncthreads();
  }
}

// ---------------------------------------------------------------------------
// K2: q/k/v GEMM with XCD-aware 1D swizzle (round-5 proven structure).
// ---------------------------------------------------------------------------
__global__ __launch_bounds__(256) void qkv_mfma_sw(
    const unsigned short* __restrict__ xsb, const unsigned short* __restrict__ wsp,
    const float* __restrict__ bnw,
    uint8_t* __restrict__ qs, uint8_t* __restrict__ ks_, uint8_t* __restrict__ vs) {
  __shared__ __align__(16) char smem[16384];
  char* smA = smem;
  char* smB = smem + 8192;
  const int t = threadIdx.x;
  const int L = t & 63, w = t >> 6;
  const int wrow = w >> 1, wcol = w & 1;
  const int b = blockIdx.x;
  const int oct = b / 48, rem = b % 48;
  const int s = rem >> 3, gl = rem & 7;
  const int g = oct * 8 + gl;
  const int ntile = g % 25, tb = g / 25;
  const int conv = s >> 1, rt = s & 1;
  const int n0 = ntile * 128;

  const char* Bb = (const char*)(xsb + (size_t)tb * XSB_TB) + (size_t)ntile * 65536;

  f32x4 acc[4][4];
#pragma unroll
  for (int i = 0; i < 4; ++i)
#pragma unroll
    for (int j = 0; j < 4; ++j) acc[i][j] = (f32x4){0.f, 0.f, 0.f, 0.f};

  for (int sp = 0; sp < 3; ++sp) {
    const char* Asp = (const char*)wsp + ((size_t)(conv * 3 + sp) * 16 + rt * 8) * 8192;
#pragma unroll 1
    for (int ks2 = 0; ks2 < 8; ++ks2) {
      __syncthreads();
      const char* Ak = Asp + ks2 * 8192;
      glds16(Ak + t * 16, smA + t * 16);
      glds16(Ak + t * 16 + 4096, smA + t * 16 + 4096);
      const char* Bk = Bb + ks2 * 1024;
      glds16(Bk + (size_t)w * 8192 + L * 16, smB + t * 16);
      glds16(Bk + (size_t)(w + 4) * 8192 + L * 16, smB + t * 16 + 4096);
      __syncthreads();
      bf16x8 af[4], bfr[4];
#pragma unroll
      for (int i = 0; i < 4; ++i) {
        af[i] = *(const bf16x8*)(smA + (wrow * 4 + i) * 1024 + L * 16);
        bfr[i] = *(const bf16x8*)(smB + (wcol * 4 + i) * 1024 + L * 16);
      }
#pragma unroll
      for (int i = 0; i < 4; ++i)
#pragma unroll
        for (int j = 0; j < 4; ++j)
          acc[i][j] = __builtin_amdgcn_mfma_f32_16x16x32_bf16(af[i], bfr[j], acc[i][j], 0, 0, 0);
    }
  }

  uint8_t* outp = (conv == 0 ? qs : (conv == 1 ? ks_ : vs)) + (size_t)tb * TBC;
  const float* sbn = bnw + conv * 512;
  const int rbase = rt * 128;
#pragma unroll
  for (int i = 0; i < 4; ++i) {
    int co0 = rbase + wrow * 64 + i * 16 + ((L >> 4) << 2);
#pragma unroll
    for (int j = 0; j < 4; ++j) {
      int n = n0 + wcol * 64 + j * 16 + (L & 15);
      if (n < N_) {
#pragma unroll
        for (int r = 0; r < 4; ++r) {
          int co = co0 + r;
          float y = acc[i][j][r] * 0.125f;
          float tt = __fadd_rn(__fmul_rn(y, sbn[co]), sbn[256 + co]);
          float rr = fminf(fmaxf(rintf(tt), 0.f), 8.f);
          outp[(size_t)co * N_ + n] = (uint8_t)rr;
        }
      }
    }
  }
}

// ---------------------------------------------------------------------------
// K3a: zero the kv accumulators living in osb's padding groups (196..199/tb)
// ---------------------------------------------------------------------------
__global__ void zero_kv(unsigned short* __restrict__ osb) {
  int tb = blockIdx.x;
  int4* p = (int4*)(osb + (size_t)tb * XSB_TB + 802816);
  for (int i = threadIdx.x; i < 2048; i += 256) p[i] = make_int4(0, 0, 0, 0);
}

// ---------------------------------------------------------------------------
// K3b: partial kv = k^T v over an n-chunk, exact i32 atomics. grid (8,32,PARTS)
// ---------------------------------------------------------------------------
__global__ __launch_bounds__(256) void attn_kv(
    const uint8_t* __restrict__ ks, const uint8_t* __restrict__ vs,
    unsigned short* __restrict__ osb) {
  const int h = blockIdx.x, tb = blockIdx.y, part = blockIdx.z;
  const int tid = threadIdx.x;
  __shared__ unsigned sk[32][64];
  __shared__ unsigned sv[32][64];
  const uint8_t* K = ks + (size_t)tb * TBC + h * 32 * N_;
  const uint8_t* V = vs + (size_t)tb * TBC + h * 32 * N_;
  const int d0 = (tid >> 4) * 2;
  const int e0 = (tid & 15) * 2;
  const int pbase = part * CHUNK;
  const int pend = pbase + CHUNK;
  int acc[2][2] = {};

  for (int nt = 0; nt < 2; ++nt) {     // 448 = 256 + 192
    int n0 = pbase + nt * 256;
    if (n0 >= pend) break;
    if (nt) __syncthreads();
#pragma unroll
    for (int i = 0; i < 8; ++i) {
      int idx = tid + i * 256;
      int d = idx >> 6, w2 = idx & 63;
      int n = n0 + w2 * 4;
      unsigned kw_ = 0, vw_ = 0;
      if (n < pend) {
        kw_ = *(const unsigned*)&K[d * N_ + n];
        vw_ = *(const unsigned*)&V[d * N_ + n];
      }
      sk[d][w2] = kw_;
      sv[d][w2] = vw_;
    }
    __syncthreads();
#pragma unroll
    for (int w2 = 0; w2 < 64; w2 += 4) {
      uint4 ka = *(const uint4*)&sk[d0][w2];
      uint4 kb = *(const uint4*)&sk[d0 + 1][w2];
      uint4 va = *(const uint4*)&sv[e0][w2];
      uint4 vb = *(const uint4*)&sv[e0 + 1][w2];
      unsigned kwds[2][4] = {{ka.x, ka.y, ka.z, ka.w}, {kb.x, kb.y, kb.z, kb.w}};
      unsigned vwds[2][4] = {{va.x, va.y, va.z, va.w}, {vb.x, vb.y, vb.z, vb.w}};
#pragma unroll
      for (int di = 0; di < 2; ++di)
#pragma unroll
        for (int ej = 0; ej < 2; ++ej)
#pragma unroll
          for (int c = 0; c < 4; ++c)
            acc[di][ej] = dot4(kwds[di][c], vwds[ej][c], acc[di][ej]);
    }
  }
  int* dst = (int*)(osb + (size_t)tb * XSB_TB + 802816) + h * 1024;
  atomicAdd(&dst[d0 * 32 + e0], acc[0][0]);
  atomicAdd(&dst[d0 * 32 + e0 + 1], acc[0][1]);
  atomicAdd(&dst[(d0 + 1) * 32 + e0], acc[1][0]);
  atomicAdd(&dst[(d0 + 1) * 32 + e0 + 1], acc[1][1]);
}

// ---------------------------------------------------------------------------
// K3c: o = quant(q . kv * scale) -> blocked bf16 layout, now with LDS repack
// and fully-coalesced uint4 stores (16-px group = 1KB contiguous per head).
// grid (8,32,PARTS)
// ---------------------------------------------------------------------------
__global__ __launch_bounds__(256) void attn_o(
    const uint8_t* __restrict__ qs, unsigned short* __restrict__ osb) {
  const int h = blockIdx.x, tb = blockIdx.y, part = blockIdx.z;
  const int tid = threadIdx.x;
  __shared__ uint8_t sq[256][48];
  __shared__ __align__(16) unsigned short so[16 * 544];  // [gi][eq*136 + n16*8 + e7], padded
  const uint8_t* Q = qs + (size_t)tb * TBC + h * 32 * N_;
  unsigned short* osb_tb = osb + (size_t)tb * XSB_TB;
  const int e = tid & 31;
  const int g2 = tid >> 5;
  const int eq = e >> 3, e7 = e & 7;
  const int* kvp = (const int*)(osb + (size_t)tb * XSB_TB + 802816) + h * 1024;
  int kvcol[32];
#pragma unroll
  for (int d = 0; d < 32; ++d) kvcol[d] = kvp[d * 32 + e];

  const float cscale = (float)(0.3535533905932738 / 512.0);
  const int pbase = part * CHUNK;
  const int pend = pbase + CHUNK;

  for (int nt = 0; nt < 2; ++nt) {
    int n0 = pbase + nt * 256;
    if (n0 >= pend) break;
    if (nt) __syncthreads();
    // stage q[32d][<=256n] transposed to sq[n][d]
#pragma unroll
    for (int i = 0; i < 8; ++i) {
      int idx = tid + i * 256;
      int d = idx >> 6, w2 = idx & 63;
      int n = n0 + w2 * 4;
      unsigned qw_ = 0;
      if (n < pend) qw_ = *(const unsigned*)&Q[d * N_ + n];
      sq[w2 * 4 + 0][d] = (uint8_t)(qw_ & 255u);
      sq[w2 * 4 + 1][d] = (uint8_t)((qw_ >> 8) & 255u);
      sq[w2 * 4 + 2][d] = (uint8_t)((qw_ >> 16) & 255u);
      sq[w2 * 4 + 3][d] = (uint8_t)(qw_ >> 24);
    }
    __syncthreads();
#pragma unroll
    for (int s8 = 0; s8 < 8; ++s8) {
      int nl = (s8 * 8 + g2) * 4;
      int n = n0 + nl;
      if (n >= pend) continue;
      unsigned short* sop = &so[(nl >> 4) * 544 + eq * 136 + (nl & 15) * 8 + e7];
#pragma unroll
      for (int jn = 0; jn < 4; ++jn) {
        const uint8_t* qrow = &sq[nl + jn][0];
        uint4 qa = *(const uint4*)&qrow[0];
        uint4 qb = *(const uint4*)&qrow[16];
        unsigned qq[8] = {qa.x, qa.y, qa.z, qa.w, qb.x, qb.y, qb.z, qb.w};
        int o = 0;
#pragma unroll
        for (int qi = 0; qi < 8; ++qi)
#pragma unroll
          for (int m = 0; m < 4; ++m)
            o += (int)((qq[qi] >> (8 * m)) & 255u) * kvcol[qi * 4 + m];
        float of = (float)o * cscale;
        float r = fminf(fmaxf(rintf(of), 0.f), 8.f);
        sop[jn * 8] = (unsigned short)(__float_as_uint(r) >> 16);
      }
    }
    __syncthreads();
    // cooperative coalesced store: per group 512 u16 = 64 uint4 contiguous
    int ngroups = (pend - n0) >> 4;
    if (ngroups > 16) ngroups = 16;
    int g0 = n0 >> 4;
#pragma unroll
    for (int i = 0; i < 4; ++i) {
      int idx = tid + i * 256;      // 0..1023
      int gi = idx >> 6, r = idx & 63;
      if (gi < ngroups) {
        int eqq = r >> 4, rest = (r & 15) * 8;
        uint4 v = *(const uint4*)&so[gi * 544 + eqq * 136 + rest];
        *(uint4*)&osb_tb[(size_t)(g0 + gi) * 4096 + h * 512 + r * 8] = v;
      }
    }
  }
}

// ---------------------------------------------------------------------------
// K4: out = BN(pw @ os/8) via bf16 MFMA, 2 splits (error ~1e-4 << 9.1e-3
// threshold at bf16 output granularity). XCD swizzle as before.
// ---------------------------------------------------------------------------
__global__ __launch_bounds__(256) void out_mfma_sw(
    const unsigned short* __restrict__ osb, const unsigned short* __restrict__ wsp,
    const float* __restrict__ bnw, float* __restrict__ out) {
  __shared__ __align__(16) char smem[16384];
  char* smA = smem;
  char* smB = smem + 8192;
  const int t = threadIdx.x;
  const int L = t & 63, w = t >> 6;
  const int wrow = w >> 1, wcol = w & 1;
  const int b = blockIdx.x;
  const int oct = b / 16, rem = b % 16;
  const int rt = rem >> 3, gl = rem & 7;
  const int g = oct * 8 + gl;
  const int ntile = g % 25, tb = g / 25;
  const int n0 = ntile * 128;
  const char* Bb = (const char*)(osb + (size_t)tb * XSB_TB) + (size_t)ntile * 65536;

  f32x4 acc[4][4];
#pragma unroll
  for (int i = 0; i < 4; ++i)
#pragma unroll
    for (int j = 0; j < 4; ++j) acc[i][j] = (f32x4){0.f, 0.f, 0.f, 0.f};

  for (int sp = 0; sp < 2; ++sp) {      // 2 splits suffice for the fp32 output
    const char* Asp = (const char*)wsp + ((size_t)(9 + sp) * 16 + rt * 8) * 8192;
#pragma unroll 1
    for (int ks2 = 0; ks2 < 8; ++ks2) {
      __syncthreads();
      const char* Ak = Asp + ks2 * 8192;
      glds16(Ak + t * 16, smA + t * 16);
      glds16(Ak + t * 16 + 4096, smA + t * 16 + 4096);
      const char* Bk = Bb + ks2 * 1024;
      glds16(Bk + (size_t)w * 8192 + L * 16, smB + t * 16);
      glds16(Bk + (size_t)(w + 4) * 8192 + L * 16, smB + t * 16 + 4096);
      __syncthreads();
      bf16x8 af[4], bfr[4];
#pragma unroll
      for (int i = 0; i < 4; ++i) {
        af[i] = *(const bf16x8*)(smA + (wrow * 4 + i) * 1024 + L * 16);
        bfr[i] = *(const bf16x8*)(smB + (wcol * 4 + i) * 1024 + L * 16);
      }
#pragma unroll
      for (int i = 0; i < 4; ++i)
#pragma unroll
        for (int j = 0; j < 4; ++j)
          acc[i][j] = __builtin_amdgcn_mfma_f32_16x16x32_bf16(af[i], bfr[j], acc[i][j], 0, 0, 0);
    }
  }

  float* O = out + (size_t)tb * TBC;
  const float* sbn = bnw + 3 * 512;
  const int rbase = rt * 128;
#pragma unroll
  for (int i = 0; i < 4; ++i) {
    int co0 = rbase + wrow * 64 + i * 16 + ((L >> 4) << 2);
#pragma unroll
    for (int j = 0; j < 4; ++j) {
      int n = n0 + wcol * 64 + j * 16 + (L & 15);
      if (n < N_) {
#pragma unroll
        for (int r = 0; r < 4; ++r) {
          int co = co0 + r;
          float y = acc[i][j][r] * 0.125f;
          O[(size_t)co * N_ + n] = __fadd_rn(__fmul_rn(y, sbn[co]), sbn[256 + co]);
        }
      }
    }
  }
}

// ---------------------------------------------------------------------------
extern "C" void kernel_launch(void* const* d_in, const int* in_sizes, int n_in,
                              void* d_out, int out_size, void* d_ws, size_t ws_size,
                              hipStream_t stream) {
  const float* x   = (const float*)d_in[0];
  const float* qw  = (const float*)d_in[1];
  const float* qbn = (const float*)d_in[2];
  const float* kw  = (const float*)d_in[3];
  const float* kbn = (const float*)d_in[4];
  const float* vw  = (const float*)d_in[5];
  const float* vbn = (const float*)d_in[6];
  const float* pw  = (const float*)d_in[7];
  const float* pbn = (const float*)d_in[8];
  float* out = (float*)d_out;

  uint8_t* ws = (uint8_t*)d_ws;
  float* bnw           = (float*)ws;                         // 8 KB
  unsigned short* wsp  = (unsigned short*)(ws + 8192);       // 1.57 MB
  unsigned short* xsb  = (unsigned short*)(ws + 1581056);    // 52.4 MB blocked spikes
  uint8_t* qsp = ws + 54009856;
  uint8_t* ksp = qsp + ACT_SZ;
  uint8_t* vsp = ksp + ACT_SZ;                               // ends at 131,080,192
  unsigned short* osb = xsb;   // alias: xsb dead after qkv; kv scratch in osb padding groups

  bn_prep<<<1, 256, 0, stream>>>(qbn, kbn, vbn, pbn, bnw);
  wprep<<<dim3(256, 4), 256, 0, stream>>>(qw, kw, vw, pw, wsp);
  quant_x_t<<<dim3(49, 32), 256, 0, stream>>>(x, xsb);
  qkv_mfma_sw<<<4800, 256, 0, stream>>>(xsb, wsp, bnw, qsp, ksp, vsp);
  zero_kv<<<32, 256, 0, stream>>>(osb);
  attn_kv<<<dim3(8, 32, PARTS), 256, 0, stream>>>(ksp, vsp, osb);
  attn_o<<<dim3(8, 32, PARTS), 256, 0, stream>>>(qsp, osb);
  out_mfma_sw<<<1600, 256, 0, stream>>>(osb, wsp, bnw, out);
}